// Round 1
// baseline (148.507 us; speedup 1.0000x reference)
//
#include <hip/hip_runtime.h>
#include <hip/hip_bf16.h>
#include <math.h>

// NTXent loss, N=8192 rows, D=128.
// loss = mean_i [ log(sum_{j!=i} exp(2*cos_ij)) - 2*cos_{i,partner} ]
// R9: sim_kernel is latency-bound (absent from rocprof top-5 => <42us, vs
// 2.2us of pure MFMA issue). The per-ni colsum tail (2x dependent shfl_xor +
// LDS atomic, ~200cy) sat on the MFMA->exp2 result chain 16x per tile with
// only 3 waves/SIMD to cover. Change: unroll the chunk loop, keep per-column
// partials in 16 registers (static idx), defer ALL cross-lane + LDS-atomic
// colsum work to one batched epilogue; setprio(1) around the MFMA cluster.

typedef __attribute__((ext_vector_type(8))) short bf16x8;   // 8 bf16 = 4 VGPRs
typedef __attribute__((ext_vector_type(4))) float f32x4;

#define NROWS 8192
#define DDIM  128
#define BHALF 4096
#define CHUNK 32
#define NT    32                    // 32x32 grid of 256x256 tiles
#define NBLK  528                   // 32*33/2 upper-triangle tiles
// zn scaled by sqrt(2/ln2): acc = (2/ln2)*cos, exp(2cos) = exp2(acc)
#define SQRT_E2S 1.6986435980707531f
#define TWO_LN2  1.3862943611198906f
#define EXPDIAG  7.38905609893065f

static __device__ __forceinline__ unsigned short f2bf(float f) {
  unsigned int u = __float_as_uint(f);
  unsigned int r = (u + 0x7fffu + ((u >> 16) & 1u)) >> 16;   // RNE
  return (unsigned short)r;
}

static __device__ __forceinline__ void glds16(const unsigned short* g, unsigned short* l) {
  __builtin_amdgcn_global_load_lds((const __attribute__((address_space(1))) unsigned int*)g,
                                   (__attribute__((address_space(3))) unsigned int*)l,
                                   16, 0, 0);
}

// ---- Kernel 1: normalize (scaled) + fp32 pair-dots + zero sums/out -------
// Block b: waves 0,1 -> rows 2b,2b+1 (zi); waves 2,3 -> their partners (zj).
__global__ void norm_kernel(const float* __restrict__ zi, const float* __restrict__ zj,
                            unsigned short* __restrict__ zn,
                            float* __restrict__ row_sums, float* __restrict__ pos,
                            float* __restrict__ out) {
  __shared__ float2 xbuf[2][64];
  int wave = threadIdx.x >> 6;
  int lane = threadIdx.x & 63;
  int pi   = blockIdx.x * 2 + (wave & 1);           // pair index
  int row  = pi + (wave >> 1) * BHALF;
  const float* src = (row < BHALF) ? (zi + (size_t)row * DDIM)
                                   : (zj + (size_t)(row - BHALF) * DDIM);
  float2 v = *(const float2*)(src + 2 * lane);
  float ss = v.x * v.x + v.y * v.y;
  #pragma unroll
  for (int off = 1; off < 64; off <<= 1) ss += __shfl_xor(ss, off);
  float scale = SQRT_E2S / fmaxf(sqrtf(ss), 1e-8f);
  v.x *= scale; v.y *= scale;
  unsigned int lo = f2bf(v.x), hi = f2bf(v.y);
  ((unsigned int*)(zn + (size_t)row * DDIM))[lane] = lo | (hi << 16);

  if (wave >= 2) xbuf[wave - 2][lane] = v;
  __syncthreads();
  if (wave < 2) {                                    // d = (2/ln2)*cos(i, i+B)
    float2 w = xbuf[wave][lane];
    float d = v.x * w.x + v.y * w.y;
    #pragma unroll
    for (int off = 1; off < 64; off <<= 1) d += __shfl_xor(d, off);
    if (lane == 0) pos[pi] = d;
  }
  if (threadIdx.x < 4) row_sums[blockIdx.x * 4 + threadIdx.x] = 0.0f;
  if (blockIdx.x == 0 && threadIdx.x == 4) out[0] = 0.0f;
}

// ---- Kernel 2: upper-triangle sim + exp + row/col sums -------------------
// 528 blocks (triangle map), 256x256 tiles, 4 waves x 64 rows, A in regs,
// B in 32-col chunks double-buffered via global_load_lds (XOR swizzle).
// Column sums accumulate in 16 registers per thread (one per 16-col group);
// all cross-lane reduction deferred to the block epilogue.
__global__ __launch_bounds__(256, 3)
void sim_kernel(const unsigned short* __restrict__ zn, float* __restrict__ row_sums) {
  __shared__ unsigned short lds[2 * CHUNK * DDIM];   // 2 x 8 KB
  __shared__ float colsum[256];

  // linear block id -> upper-triangle (tx <= ty) over NT x NT
  int t = blockIdx.x;
  int tx = (int)((65.0f - sqrtf((float)(4225 - 8 * t))) * 0.5f);
  while ((tx + 1) * NT - ((tx + 1) * tx) / 2 <= t) ++tx;
  while (tx * NT - (tx * (tx - 1)) / 2 > t) --tx;
  const int ty = t - (tx * NT - (tx * (tx - 1)) / 2) + tx;
  const bool diag = (tx == ty);

  const int wave = threadIdx.x >> 6;
  const int lane = threadIdx.x & 63;
  const int l15  = lane & 15;
  const int quad = lane >> 4;

  const int row_base = tx * 256 + wave * 64;
  const int col_base = ty * 256;

  colsum[threadIdx.x] = 0.0f;

  // A fragments: A[m=l15][k=quad*8+j], 4 mi-tiles x 4 k-frags = 64 VGPRs
  bf16x8 a[4][4];
  const unsigned short* abase = zn + (size_t)(row_base + l15) * DDIM + quad * 8;
  #pragma unroll
  for (int mi = 0; mi < 4; ++mi)
    #pragma unroll
    for (int kf = 0; kf < 4; ++kf)
      a[mi][kf] = *(const bf16x8*)(abase + mi * 16 * DDIM + kf * 32);

  float rs[4][4];
  #pragma unroll
  for (int mi = 0; mi < 4; ++mi)
    #pragma unroll
    for (int r = 0; r < 4; ++r) rs[mi][r] = 0.0f;

  // Per-thread column partials: csr[cc] = sum over this thread's 16 rows of
  // exp for column col_base + cc*16 + l15. Static indices (ch loop unrolled).
  float csr[16];
  #pragma unroll
  for (int cc = 0; cc < 16; ++cc) csr[cc] = 0.0f;

  // Staging: buffer = 32 B-rows x 16 chunks of 16B; slot t2 -> row t2>>4,
  // chunk (t2&15)^(row&15) [XOR swizzle]. Two 256-lane issues per chunk.
  const int t0 = wave * 64 + lane;
  const int r0 = t0 >> 4,         c0 = (t0 & 15) ^ (r0 & 15);
  const int r1 = (t0 + 256) >> 4, c1 = (t0 & 15) ^ (r1 & 15);
  const unsigned short* gst0 = zn + (size_t)(col_base + r0) * DDIM + c0 * 8;
  const unsigned short* gst1 = zn + (size_t)(col_base + r1) * DDIM + c1 * 8;

  int rdoff[4];
  #pragma unroll
  for (int kf = 0; kf < 4; ++kf)
    rdoff[kf] = l15 * DDIM + (((quad + 4 * kf) ^ l15) << 3);

  glds16(gst0, lds + wave * 512);                    // prime chunk 0 -> buf 0
  glds16(gst1, lds + 2048 + wave * 512);
  __syncthreads();

  #pragma unroll
  for (int ch = 0; ch < 8; ++ch) {
    const int buf = ch & 1;
    if (ch < 7) {                                    // stage chunk ch+1
      const unsigned short* g0 = gst0 + (size_t)(ch + 1) * CHUNK * DDIM;
      const unsigned short* g1 = gst1 + (size_t)(ch + 1) * CHUNK * DDIM;
      unsigned short* lb = lds + ((ch + 1) & 1) * 4096;
      glds16(g0, lb + wave * 512);
      glds16(g1, lb + 2048 + wave * 512);
    }
    const unsigned short* lb = lds + buf * 4096;
    #pragma unroll
    for (int ni = 0; ni < 2; ++ni) {
      bf16x8 b[4];
      #pragma unroll
      for (int kf = 0; kf < 4; ++kf)
        b[kf] = *(const bf16x8*)(lb + ni * 16 * DDIM + rdoff[kf]);
      f32x4 acc[4];
      __builtin_amdgcn_s_setprio(1);
      #pragma unroll
      for (int mi = 0; mi < 4; ++mi) {
        f32x4 z = {0.0f, 0.0f, 0.0f, 0.0f};
        acc[mi] = __builtin_amdgcn_mfma_f32_16x16x32_bf16(a[mi][0], b[0], z, 0, 0, 0);
      }
      #pragma unroll
      for (int kf = 1; kf < 4; ++kf)
        #pragma unroll
        for (int mi = 0; mi < 4; ++mi)
          acc[mi] = __builtin_amdgcn_mfma_f32_16x16x32_bf16(a[mi][kf], b[kf], acc[mi], 0, 0, 0);
      __builtin_amdgcn_s_setprio(0);
      // e feeds this row's sum and the column partial (register, no shfl).
      #pragma unroll
      for (int mi = 0; mi < 4; ++mi)
        #pragma unroll
        for (int r = 0; r < 4; ++r) {
          float e = __builtin_amdgcn_exp2f(acc[mi][r]);
          rs[mi][r] += e;
          csr[ch * 2 + ni] += e;
        }
    }
    if (ch < 7) __syncthreads();
  }

  // Column epilogue: quad-reduce each of the 16 partials, aggregate in LDS.
  if (!diag) {
    #pragma unroll
    for (int cc = 0; cc < 16; ++cc) {
      float v = csr[cc];
      v += __shfl_xor(v, 16);
      v += __shfl_xor(v, 32);
      if (quad == 0) atomicAdd(&colsum[cc * 16 + l15], v);
    }
  }
  __syncthreads();

  // Row side. C/D layout: col=l15, row=quad*4+reg.
  #pragma unroll
  for (int mi = 0; mi < 4; ++mi)
    #pragma unroll
    for (int r = 0; r < 4; ++r) {
      float v = rs[mi][r];
      v += __shfl_xor(v, 1);
      v += __shfl_xor(v, 2);
      v += __shfl_xor(v, 4);
      v += __shfl_xor(v, 8);
      if (l15 == 0)
        atomicAdd(&row_sums[row_base + mi * 16 + quad * 4 + r], v);
    }
  // Col side: one atomic per col per block (transposed rows).
  if (!diag)
    atomicAdd(&row_sums[col_base + threadIdx.x], colsum[threadIdx.x]);
}

// ---- Kernel 3: logs + mean (pos already fp32 from norm) ------------------
__global__ void finalize_kernel(const float* __restrict__ row_sums,
                                const float* __restrict__ pos,
                                float* __restrict__ out) {
  __shared__ float red[4];
  int i = blockIdx.x * 256 + threadIdx.x;            // grid 16 x 256 = 4096 pairs
  float si = row_sums[i] - EXPDIAG;
  float sp = row_sums[i + BHALF] - EXPDIAG;
  float v = logf(si) + logf(sp) - TWO_LN2 * pos[i];
  #pragma unroll
  for (int off = 1; off < 64; off <<= 1) v += __shfl_xor(v, off);
  int wave = threadIdx.x >> 6, lane = threadIdx.x & 63;
  if (lane == 0) red[wave] = v;
  __syncthreads();
  if (threadIdx.x == 0)
    atomicAdd(out, (red[0] + red[1] + red[2] + red[3]) * (1.0f / 8192.0f));
}

extern "C" void kernel_launch(void* const* d_in, const int* in_sizes, int n_in,
                              void* d_out, int out_size, void* d_ws, size_t ws_size,
                              hipStream_t stream) {
  const float* zi = (const float*)d_in[0];
  const float* zj = (const float*)d_in[1];
  char* ws = (char*)d_ws;
  unsigned short* zn = (unsigned short*)ws;                    // 2 MB
  float* row_sums = (float*)(ws + (size_t)NROWS * DDIM * 2);   // 32 KB
  float* pos      = (float*)(ws + (size_t)NROWS * DDIM * 2 + NROWS * 4);  // 16 KB
  float* out = (float*)d_out;

  norm_kernel<<<2048, 256, 0, stream>>>(zi, zj, zn, row_sums, pos, out);
  sim_kernel<<<NBLK, 256, 0, stream>>>(zn, row_sums);
  finalize_kernel<<<16, 256, 0, stream>>>(row_sums, pos, out);
}

// Round 2
// 108.301 us; speedup vs baseline: 1.3713x; 1.3713x over previous
//
#include <hip/hip_runtime.h>
#include <hip/hip_bf16.h>
#include <math.h>

// NTXent loss, N=8192 rows, D=128.
// loss = mean_i [ log(sum_{j!=i} exp(2*cos_ij)) - 2*cos_{i,partner} ]
// R10: R9's register-array colsum (csr[16] + full unroll) re-tripped the
// allocator cliff (VGPR 84, 94 MB scratch writes, MfmaUtil 3.3% -- same
// signature as R7). Revert to R6 structure (dynamic ch loop, no unroll
// pragma, no setprio) and defer the colsum differently: each per-ni partial
// cs targets a UNIQUE LDS slot colpart[wave*4+quad][cc*16+l15] (cc visited
// once per thread), so the per-ni tail becomes one fire-and-forget
// ds_write_b32 -- no shfl chain, no atomic, zero extra registers. One
// 16-way reduction per column in the block epilogue.

typedef __attribute__((ext_vector_type(8))) short bf16x8;   // 8 bf16 = 4 VGPRs
typedef __attribute__((ext_vector_type(4))) float f32x4;

#define NROWS 8192
#define DDIM  128
#define BHALF 4096
#define CHUNK 32
#define NT    32                    // 32x32 grid of 256x256 tiles
#define NBLK  528                   // 32*33/2 upper-triangle tiles
#define CPAD  264                   // 256 + 8: breaks quad-bank aliasing
// zn scaled by sqrt(2/ln2): acc = (2/ln2)*cos, exp(2cos) = exp2(acc)
#define SQRT_E2S 1.6986435980707531f
#define TWO_LN2  1.3862943611198906f
#define EXPDIAG  7.38905609893065f

static __device__ __forceinline__ unsigned short f2bf(float f) {
  unsigned int u = __float_as_uint(f);
  unsigned int r = (u + 0x7fffu + ((u >> 16) & 1u)) >> 16;   // RNE
  return (unsigned short)r;
}

static __device__ __forceinline__ void glds16(const unsigned short* g, unsigned short* l) {
  __builtin_amdgcn_global_load_lds((const __attribute__((address_space(1))) unsigned int*)g,
                                   (__attribute__((address_space(3))) unsigned int*)l,
                                   16, 0, 0);
}

// ---- Kernel 1: normalize (scaled) + fp32 pair-dots + zero sums/out -------
// Block b: waves 0,1 -> rows 2b,2b+1 (zi); waves 2,3 -> their partners (zj).
__global__ void norm_kernel(const float* __restrict__ zi, const float* __restrict__ zj,
                            unsigned short* __restrict__ zn,
                            float* __restrict__ row_sums, float* __restrict__ pos,
                            float* __restrict__ out) {
  __shared__ float2 xbuf[2][64];
  int wave = threadIdx.x >> 6;
  int lane = threadIdx.x & 63;
  int pi   = blockIdx.x * 2 + (wave & 1);           // pair index
  int row  = pi + (wave >> 1) * BHALF;
  const float* src = (row < BHALF) ? (zi + (size_t)row * DDIM)
                                   : (zj + (size_t)(row - BHALF) * DDIM);
  float2 v = *(const float2*)(src + 2 * lane);
  float ss = v.x * v.x + v.y * v.y;
  #pragma unroll
  for (int off = 1; off < 64; off <<= 1) ss += __shfl_xor(ss, off);
  float scale = SQRT_E2S / fmaxf(sqrtf(ss), 1e-8f);
  v.x *= scale; v.y *= scale;
  unsigned int lo = f2bf(v.x), hi = f2bf(v.y);
  ((unsigned int*)(zn + (size_t)row * DDIM))[lane] = lo | (hi << 16);

  if (wave >= 2) xbuf[wave - 2][lane] = v;
  __syncthreads();
  if (wave < 2) {                                    // d = (2/ln2)*cos(i, i+B)
    float2 w = xbuf[wave][lane];
    float d = v.x * w.x + v.y * w.y;
    #pragma unroll
    for (int off = 1; off < 64; off <<= 1) d += __shfl_xor(d, off);
    if (lane == 0) pos[pi] = d;
  }
  if (threadIdx.x < 4) row_sums[blockIdx.x * 4 + threadIdx.x] = 0.0f;
  if (blockIdx.x == 0 && threadIdx.x == 4) out[0] = 0.0f;
}

// ---- Kernel 2: upper-triangle sim + exp + row/col sums -------------------
// 528 blocks (triangle map), 256x256 tiles, 4 waves x 64 rows, A in regs,
// B in 32-col chunks double-buffered via global_load_lds (XOR swizzle).
__global__ __launch_bounds__(256, 3)
void sim_kernel(const unsigned short* __restrict__ zn, float* __restrict__ row_sums) {
  __shared__ unsigned short lds[2 * CHUNK * DDIM];   // 2 x 8 KB
  __shared__ float colpart[16][CPAD];                // [wave*4+quad][col] ~16.9 KB

  // linear block id -> upper-triangle (tx <= ty) over NT x NT
  int t = blockIdx.x;
  int tx = (int)((65.0f - sqrtf((float)(4225 - 8 * t))) * 0.5f);
  while ((tx + 1) * NT - ((tx + 1) * tx) / 2 <= t) ++tx;
  while (tx * NT - (tx * (tx - 1)) / 2 > t) --tx;
  const int ty = t - (tx * NT - (tx * (tx - 1)) / 2) + tx;
  const bool diag = (tx == ty);

  const int wave = threadIdx.x >> 6;
  const int lane = threadIdx.x & 63;
  const int l15  = lane & 15;
  const int quad = lane >> 4;

  const int row_base = tx * 256 + wave * 64;
  const int col_base = ty * 256;

  // A fragments: A[m=l15][k=quad*8+j], 4 mi-tiles x 4 k-frags = 64 VGPRs
  bf16x8 a[4][4];
  const unsigned short* abase = zn + (size_t)(row_base + l15) * DDIM + quad * 8;
  #pragma unroll
  for (int mi = 0; mi < 4; ++mi)
    #pragma unroll
    for (int kf = 0; kf < 4; ++kf)
      a[mi][kf] = *(const bf16x8*)(abase + mi * 16 * DDIM + kf * 32);

  float rs[4][4];
  #pragma unroll
  for (int mi = 0; mi < 4; ++mi)
    #pragma unroll
    for (int r = 0; r < 4; ++r) rs[mi][r] = 0.0f;

  // Staging: buffer = 32 B-rows x 16 chunks of 16B; slot t2 -> row t2>>4,
  // chunk (t2&15)^(row&15) [XOR swizzle]. Two 256-lane issues per chunk.
  const int t0 = wave * 64 + lane;
  const int r0 = t0 >> 4,         c0 = (t0 & 15) ^ (r0 & 15);
  const int r1 = (t0 + 256) >> 4, c1 = (t0 & 15) ^ (r1 & 15);
  const unsigned short* gst0 = zn + (size_t)(col_base + r0) * DDIM + c0 * 8;
  const unsigned short* gst1 = zn + (size_t)(col_base + r1) * DDIM + c1 * 8;

  int rdoff[4];
  #pragma unroll
  for (int kf = 0; kf < 4; ++kf)
    rdoff[kf] = l15 * DDIM + (((quad + 4 * kf) ^ l15) << 3);

  // Per-thread colpart row base: slot s = wave*4+quad, column written per ni
  // is cc*16 + l15 (cc = ch*2+ni visited exactly once per thread -> plain store).
  float* cp = &colpart[wave * 4 + quad][l15];

  glds16(gst0, lds + wave * 512);                    // prime chunk 0 -> buf 0
  glds16(gst1, lds + 2048 + wave * 512);
  __syncthreads();

  for (int ch = 0; ch < 8; ++ch) {
    const int buf = ch & 1;
    if (ch < 7) {                                    // stage chunk ch+1
      const unsigned short* g0 = gst0 + (size_t)(ch + 1) * CHUNK * DDIM;
      const unsigned short* g1 = gst1 + (size_t)(ch + 1) * CHUNK * DDIM;
      unsigned short* lb = lds + ((ch + 1) & 1) * 4096;
      glds16(g0, lb + wave * 512);
      glds16(g1, lb + 2048 + wave * 512);
    }
    const unsigned short* lb = lds + buf * 4096;
    #pragma unroll
    for (int ni = 0; ni < 2; ++ni) {
      bf16x8 b[4];
      #pragma unroll
      for (int kf = 0; kf < 4; ++kf)
        b[kf] = *(const bf16x8*)(lb + ni * 16 * DDIM + rdoff[kf]);
      f32x4 acc[4];
      #pragma unroll
      for (int mi = 0; mi < 4; ++mi) {
        f32x4 z = {0.0f, 0.0f, 0.0f, 0.0f};
        acc[mi] = __builtin_amdgcn_mfma_f32_16x16x32_bf16(a[mi][0], b[0], z, 0, 0, 0);
      }
      #pragma unroll
      for (int kf = 1; kf < 4; ++kf)
        #pragma unroll
        for (int mi = 0; mi < 4; ++mi)
          acc[mi] = __builtin_amdgcn_mfma_f32_16x16x32_bf16(a[mi][kf], b[kf], acc[mi], 0, 0, 0);
      // e feeds this row's sum and (via colpart) the transposed row's sum.
      float cs = 0.0f;
      #pragma unroll
      for (int mi = 0; mi < 4; ++mi)
        #pragma unroll
        for (int r = 0; r < 4; ++r) {
          float e = __builtin_amdgcn_exp2f(acc[mi][r]);
          rs[mi][r] += e;
          cs += e;
        }
      cp[(ch * 2 + ni) * 16] = cs;                   // unique slot: plain store
    }
    __syncthreads();
  }

  // Row side. C/D layout: col=l15, row=quad*4+reg.
  #pragma unroll
  for (int mi = 0; mi < 4; ++mi)
    #pragma unroll
    for (int r = 0; r < 4; ++r) {
      float v = rs[mi][r];
      v += __shfl_xor(v, 1);
      v += __shfl_xor(v, 2);
      v += __shfl_xor(v, 4);
      v += __shfl_xor(v, 8);
      if (l15 == 0)
        atomicAdd(&row_sums[row_base + mi * 16 + quad * 4 + r], v);
    }
  // Col side: reduce 16 slots per column, one atomic per col per block.
  if (!diag) {
    float v = 0.0f;
    #pragma unroll
    for (int s = 0; s < 16; ++s) v += colpart[s][threadIdx.x];
    atomicAdd(&row_sums[col_base + threadIdx.x], v);
  }
}

// ---- Kernel 3: logs + mean (pos already fp32 from norm) ------------------
__global__ void finalize_kernel(const float* __restrict__ row_sums,
                                const float* __restrict__ pos,
                                float* __restrict__ out) {
  __shared__ float red[4];
  int i = blockIdx.x * 256 + threadIdx.x;            // grid 16 x 256 = 4096 pairs
  float si = row_sums[i] - EXPDIAG;
  float sp = row_sums[i + BHALF] - EXPDIAG;
  float v = logf(si) + logf(sp) - TWO_LN2 * pos[i];
  #pragma unroll
  for (int off = 1; off < 64; off <<= 1) v += __shfl_xor(v, off);
  int wave = threadIdx.x >> 6, lane = threadIdx.x & 63;
  if (lane == 0) red[wave] = v;
  __syncthreads();
  if (threadIdx.x == 0)
    atomicAdd(out, (red[0] + red[1] + red[2] + red[3]) * (1.0f / 8192.0f));
}

extern "C" void kernel_launch(void* const* d_in, const int* in_sizes, int n_in,
                              void* d_out, int out_size, void* d_ws, size_t ws_size,
                              hipStream_t stream) {
  const float* zi = (const float*)d_in[0];
  const float* zj = (const float*)d_in[1];
  char* ws = (char*)d_ws;
  unsigned short* zn = (unsigned short*)ws;                    // 2 MB
  float* row_sums = (float*)(ws + (size_t)NROWS * DDIM * 2);   // 32 KB
  float* pos      = (float*)(ws + (size_t)NROWS * DDIM * 2 + NROWS * 4);  // 16 KB
  float* out = (float*)d_out;

  norm_kernel<<<2048, 256, 0, stream>>>(zi, zj, zn, row_sums, pos, out);
  sim_kernel<<<NBLK, 256, 0, stream>>>(zn, row_sums);
  finalize_kernel<<<16, 256, 0, stream>>>(row_sums, pos, out);
}

// Round 3
// 95.352 us; speedup vs baseline: 1.5575x; 1.1358x over previous
//
#include <hip/hip_runtime.h>
#include <hip/hip_bf16.h>
#include <math.h>

// NTXent loss, N=8192 rows, D=128.
// loss = mean_i [ log(sum_{j!=i} exp(2*cos_ij)) - 2*cos_{i,partner} ]
// R11: the spill never left. R10 (and by VGPR=84 signature, R6/R8 too)
// spills the A-frags: VGPR 84 + 74 MB scratch writes on a 2 MB-working-set
// kernel. Cause: __launch_bounds__(256,3) caps the allocator at 168 VGPRs,
// right at the ~150-170 live-state edge, and it collapses to 84+scratch.
// The ,3 occupancy is unusable anyway: 528 blocks / 256 CUs = 2.06/CU
// (measured occupancy 16.8%, grid-limited). Change: (256,2) -> 256-VGPR cap.
// Everything else identical to R10.

typedef __attribute__((ext_vector_type(8))) short bf16x8;   // 8 bf16 = 4 VGPRs
typedef __attribute__((ext_vector_type(4))) float f32x4;

#define NROWS 8192
#define DDIM  128
#define BHALF 4096
#define CHUNK 32
#define NT    32                    // 32x32 grid of 256x256 tiles
#define NBLK  528                   // 32*33/2 upper-triangle tiles
#define CPAD  264                   // 256 + 8: breaks quad-bank aliasing
// zn scaled by sqrt(2/ln2): acc = (2/ln2)*cos, exp(2cos) = exp2(acc)
#define SQRT_E2S 1.6986435980707531f
#define TWO_LN2  1.3862943611198906f
#define EXPDIAG  7.38905609893065f

static __device__ __forceinline__ unsigned short f2bf(float f) {
  unsigned int u = __float_as_uint(f);
  unsigned int r = (u + 0x7fffu + ((u >> 16) & 1u)) >> 16;   // RNE
  return (unsigned short)r;
}

static __device__ __forceinline__ void glds16(const unsigned short* g, unsigned short* l) {
  __builtin_amdgcn_global_load_lds((const __attribute__((address_space(1))) unsigned int*)g,
                                   (__attribute__((address_space(3))) unsigned int*)l,
                                   16, 0, 0);
}

// ---- Kernel 1: normalize (scaled) + fp32 pair-dots + zero sums/out -------
// Block b: waves 0,1 -> rows 2b,2b+1 (zi); waves 2,3 -> their partners (zj).
__global__ void norm_kernel(const float* __restrict__ zi, const float* __restrict__ zj,
                            unsigned short* __restrict__ zn,
                            float* __restrict__ row_sums, float* __restrict__ pos,
                            float* __restrict__ out) {
  __shared__ float2 xbuf[2][64];
  int wave = threadIdx.x >> 6;
  int lane = threadIdx.x & 63;
  int pi   = blockIdx.x * 2 + (wave & 1);           // pair index
  int row  = pi + (wave >> 1) * BHALF;
  const float* src = (row < BHALF) ? (zi + (size_t)row * DDIM)
                                   : (zj + (size_t)(row - BHALF) * DDIM);
  float2 v = *(const float2*)(src + 2 * lane);
  float ss = v.x * v.x + v.y * v.y;
  #pragma unroll
  for (int off = 1; off < 64; off <<= 1) ss += __shfl_xor(ss, off);
  float scale = SQRT_E2S / fmaxf(sqrtf(ss), 1e-8f);
  v.x *= scale; v.y *= scale;
  unsigned int lo = f2bf(v.x), hi = f2bf(v.y);
  ((unsigned int*)(zn + (size_t)row * DDIM))[lane] = lo | (hi << 16);

  if (wave >= 2) xbuf[wave - 2][lane] = v;
  __syncthreads();
  if (wave < 2) {                                    // d = (2/ln2)*cos(i, i+B)
    float2 w = xbuf[wave][lane];
    float d = v.x * w.x + v.y * w.y;
    #pragma unroll
    for (int off = 1; off < 64; off <<= 1) d += __shfl_xor(d, off);
    if (lane == 0) pos[pi] = d;
  }
  if (threadIdx.x < 4) row_sums[blockIdx.x * 4 + threadIdx.x] = 0.0f;
  if (blockIdx.x == 0 && threadIdx.x == 4) out[0] = 0.0f;
}

// ---- Kernel 2: upper-triangle sim + exp + row/col sums -------------------
// 528 blocks (triangle map), 256x256 tiles, 4 waves x 64 rows, A in regs,
// B in 32-col chunks double-buffered via global_load_lds (XOR swizzle).
__global__ __launch_bounds__(256, 2)
void sim_kernel(const unsigned short* __restrict__ zn, float* __restrict__ row_sums) {
  __shared__ unsigned short lds[2 * CHUNK * DDIM];   // 2 x 8 KB
  __shared__ float colpart[16][CPAD];                // [wave*4+quad][col] ~16.9 KB

  // linear block id -> upper-triangle (tx <= ty) over NT x NT
  int t = blockIdx.x;
  int tx = (int)((65.0f - sqrtf((float)(4225 - 8 * t))) * 0.5f);
  while ((tx + 1) * NT - ((tx + 1) * tx) / 2 <= t) ++tx;
  while (tx * NT - (tx * (tx - 1)) / 2 > t) --tx;
  const int ty = t - (tx * NT - (tx * (tx - 1)) / 2) + tx;
  const bool diag = (tx == ty);

  const int wave = threadIdx.x >> 6;
  const int lane = threadIdx.x & 63;
  const int l15  = lane & 15;
  const int quad = lane >> 4;

  const int row_base = tx * 256 + wave * 64;
  const int col_base = ty * 256;

  // A fragments: A[m=l15][k=quad*8+j], 4 mi-tiles x 4 k-frags = 64 VGPRs
  bf16x8 a[4][4];
  const unsigned short* abase = zn + (size_t)(row_base + l15) * DDIM + quad * 8;
  #pragma unroll
  for (int mi = 0; mi < 4; ++mi)
    #pragma unroll
    for (int kf = 0; kf < 4; ++kf)
      a[mi][kf] = *(const bf16x8*)(abase + mi * 16 * DDIM + kf * 32);

  float rs[4][4];
  #pragma unroll
  for (int mi = 0; mi < 4; ++mi)
    #pragma unroll
    for (int r = 0; r < 4; ++r) rs[mi][r] = 0.0f;

  // Staging: buffer = 32 B-rows x 16 chunks of 16B; slot t2 -> row t2>>4,
  // chunk (t2&15)^(row&15) [XOR swizzle]. Two 256-lane issues per chunk.
  const int t0 = wave * 64 + lane;
  const int r0 = t0 >> 4,         c0 = (t0 & 15) ^ (r0 & 15);
  const int r1 = (t0 + 256) >> 4, c1 = (t0 & 15) ^ (r1 & 15);
  const unsigned short* gst0 = zn + (size_t)(col_base + r0) * DDIM + c0 * 8;
  const unsigned short* gst1 = zn + (size_t)(col_base + r1) * DDIM + c1 * 8;

  int rdoff[4];
  #pragma unroll
  for (int kf = 0; kf < 4; ++kf)
    rdoff[kf] = l15 * DDIM + (((quad + 4 * kf) ^ l15) << 3);

  // Per-thread colpart row base: slot s = wave*4+quad, column written per ni
  // is cc*16 + l15 (cc = ch*2+ni visited exactly once per thread -> plain store).
  float* cp = &colpart[wave * 4 + quad][l15];

  glds16(gst0, lds + wave * 512);                    // prime chunk 0 -> buf 0
  glds16(gst1, lds + 2048 + wave * 512);
  __syncthreads();

  for (int ch = 0; ch < 8; ++ch) {
    const int buf = ch & 1;
    if (ch < 7) {                                    // stage chunk ch+1
      const unsigned short* g0 = gst0 + (size_t)(ch + 1) * CHUNK * DDIM;
      const unsigned short* g1 = gst1 + (size_t)(ch + 1) * CHUNK * DDIM;
      unsigned short* lb = lds + ((ch + 1) & 1) * 4096;
      glds16(g0, lb + wave * 512);
      glds16(g1, lb + 2048 + wave * 512);
    }
    const unsigned short* lb = lds + buf * 4096;
    #pragma unroll
    for (int ni = 0; ni < 2; ++ni) {
      bf16x8 b[4];
      #pragma unroll
      for (int kf = 0; kf < 4; ++kf)
        b[kf] = *(const bf16x8*)(lb + ni * 16 * DDIM + rdoff[kf]);
      f32x4 acc[4];
      #pragma unroll
      for (int mi = 0; mi < 4; ++mi) {
        f32x4 z = {0.0f, 0.0f, 0.0f, 0.0f};
        acc[mi] = __builtin_amdgcn_mfma_f32_16x16x32_bf16(a[mi][0], b[0], z, 0, 0, 0);
      }
      #pragma unroll
      for (int kf = 1; kf < 4; ++kf)
        #pragma unroll
        for (int mi = 0; mi < 4; ++mi)
          acc[mi] = __builtin_amdgcn_mfma_f32_16x16x32_bf16(a[mi][kf], b[kf], acc[mi], 0, 0, 0);
      // e feeds this row's sum and (via colpart) the transposed row's sum.
      float cs = 0.0f;
      #pragma unroll
      for (int mi = 0; mi < 4; ++mi)
        #pragma unroll
        for (int r = 0; r < 4; ++r) {
          float e = __builtin_amdgcn_exp2f(acc[mi][r]);
          rs[mi][r] += e;
          cs += e;
        }
      cp[(ch * 2 + ni) * 16] = cs;                   // unique slot: plain store
    }
    __syncthreads();
  }

  // Row side. C/D layout: col=l15, row=quad*4+reg.
  #pragma unroll
  for (int mi = 0; mi < 4; ++mi)
    #pragma unroll
    for (int r = 0; r < 4; ++r) {
      float v = rs[mi][r];
      v += __shfl_xor(v, 1);
      v += __shfl_xor(v, 2);
      v += __shfl_xor(v, 4);
      v += __shfl_xor(v, 8);
      if (l15 == 0)
        atomicAdd(&row_sums[row_base + mi * 16 + quad * 4 + r], v);
    }
  // Col side: reduce 16 slots per column, one atomic per col per block.
  if (!diag) {
    float v = 0.0f;
    #pragma unroll
    for (int s = 0; s < 16; ++s) v += colpart[s][threadIdx.x];
    atomicAdd(&row_sums[col_base + threadIdx.x], v);
  }
}

// ---- Kernel 3: logs + mean (pos already fp32 from norm) ------------------
__global__ void finalize_kernel(const float* __restrict__ row_sums,
                                const float* __restrict__ pos,
                                float* __restrict__ out) {
  __shared__ float red[4];
  int i = blockIdx.x * 256 + threadIdx.x;            // grid 16 x 256 = 4096 pairs
  float si = row_sums[i] - EXPDIAG;
  float sp = row_sums[i + BHALF] - EXPDIAG;
  float v = logf(si) + logf(sp) - TWO_LN2 * pos[i];
  #pragma unroll
  for (int off = 1; off < 64; off <<= 1) v += __shfl_xor(v, off);
  int wave = threadIdx.x >> 6, lane = threadIdx.x & 63;
  if (lane == 0) red[wave] = v;
  __syncthreads();
  if (threadIdx.x == 0)
    atomicAdd(out, (red[0] + red[1] + red[2] + red[3]) * (1.0f / 8192.0f));
}

extern "C" void kernel_launch(void* const* d_in, const int* in_sizes, int n_in,
                              void* d_out, int out_size, void* d_ws, size_t ws_size,
                              hipStream_t stream) {
  const float* zi = (const float*)d_in[0];
  const float* zj = (const float*)d_in[1];
  char* ws = (char*)d_ws;
  unsigned short* zn = (unsigned short*)ws;                    // 2 MB
  float* row_sums = (float*)(ws + (size_t)NROWS * DDIM * 2);   // 32 KB
  float* pos      = (float*)(ws + (size_t)NROWS * DDIM * 2 + NROWS * 4);  // 16 KB
  float* out = (float*)d_out;

  norm_kernel<<<2048, 256, 0, stream>>>(zi, zj, zn, row_sums, pos, out);
  sim_kernel<<<NBLK, 256, 0, stream>>>(zn, row_sums);
  finalize_kernel<<<16, 256, 0, stream>>>(row_sums, pos, out);
}

// Round 4
// 86.526 us; speedup vs baseline: 1.7163x; 1.1020x over previous
//
#include <hip/hip_runtime.h>
#include <hip/hip_bf16.h>
#include <math.h>

// NTXent loss, N=8192 rows, D=128.
// loss = mean_i [ log(sum_{j!=i} exp(2*cos_ij)) - 2*cos_{i,partner} ]
// R12: R11 showed spill removal (122->50 MB traffic) changed nothing: sim
// stuck at 50us with ALL pipes idle (Mfma 6%, VALU 8%, HBM 12%, occ 14%).
// Latency-bound: 528 blocks = 2 blocks/CU = 2 waves/SIMD, plus 266K
// device-scope atomicAdds to one 32KB row_sums region ping-ponging lines
// across 8 non-coherent XCD L2s (50 MB @ 1 TB/s == the 50us).
// Changes: (1) 128x128 tiles -> 2080 blocks, 4x waves/CU, half the live
// registers (no spill cliff); (2) zero cross-block atomics: disjoint-writer
// partials part[64][8192] (block (tx,ty): row-sums -> slot ty, col-sums ->
// slot tx; every cell exactly one writer, no init), finalize sums 64 slots.

typedef __attribute__((ext_vector_type(8))) short bf16x8;   // 8 bf16 = 4 VGPRs
typedef __attribute__((ext_vector_type(4))) float f32x4;

#define NROWS 8192
#define DDIM  128
#define BHALF 4096
#define CHUNK 32
#define TILE  128
#define NT    64                    // 64x64 grid of 128x128 tiles
#define NBLK  2080                  // 64*65/2 upper-triangle tiles
#define CPAD  136                   // 128 + 8
// zn scaled by sqrt(2/ln2): acc = (2/ln2)*cos, exp(2cos) = exp2(acc)
#define SQRT_E2S 1.6986435980707531f
#define TWO_LN2  1.3862943611198906f
#define EXPDIAG  7.38905609893065f

static __device__ __forceinline__ unsigned short f2bf(float f) {
  unsigned int u = __float_as_uint(f);
  unsigned int r = (u + 0x7fffu + ((u >> 16) & 1u)) >> 16;   // RNE
  return (unsigned short)r;
}

static __device__ __forceinline__ void glds16(const unsigned short* g, unsigned short* l) {
  __builtin_amdgcn_global_load_lds((const __attribute__((address_space(1))) unsigned int*)g,
                                   (__attribute__((address_space(3))) unsigned int*)l,
                                   16, 0, 0);
}

// ---- Kernel 1: normalize (scaled) + fp32 pair-dots + zero out ------------
// Block b: waves 0,1 -> rows 2b,2b+1 (zi); waves 2,3 -> their partners (zj).
__global__ void norm_kernel(const float* __restrict__ zi, const float* __restrict__ zj,
                            unsigned short* __restrict__ zn,
                            float* __restrict__ pos, float* __restrict__ out) {
  __shared__ float2 xbuf[2][64];
  int wave = threadIdx.x >> 6;
  int lane = threadIdx.x & 63;
  int pi   = blockIdx.x * 2 + (wave & 1);           // pair index
  int row  = pi + (wave >> 1) * BHALF;
  const float* src = (row < BHALF) ? (zi + (size_t)row * DDIM)
                                   : (zj + (size_t)(row - BHALF) * DDIM);
  float2 v = *(const float2*)(src + 2 * lane);
  float ss = v.x * v.x + v.y * v.y;
  #pragma unroll
  for (int off = 1; off < 64; off <<= 1) ss += __shfl_xor(ss, off);
  float scale = SQRT_E2S / fmaxf(sqrtf(ss), 1e-8f);
  v.x *= scale; v.y *= scale;
  unsigned int lo = f2bf(v.x), hi = f2bf(v.y);
  ((unsigned int*)(zn + (size_t)row * DDIM))[lane] = lo | (hi << 16);

  if (wave >= 2) xbuf[wave - 2][lane] = v;
  __syncthreads();
  if (wave < 2) {                                    // d = (2/ln2)*cos(i, i+B)
    float2 w = xbuf[wave][lane];
    float d = v.x * w.x + v.y * w.y;
    #pragma unroll
    for (int off = 1; off < 64; off <<= 1) d += __shfl_xor(d, off);
    if (lane == 0) pos[pi] = d;
  }
  if (blockIdx.x == 0 && threadIdx.x == 0) out[0] = 0.0f;
}

// ---- Kernel 2: upper-triangle sim + exp + row/col partial sums -----------
// 2080 blocks (triangle map over 64x64), 128x128 tiles, 4 waves x 32 rows,
// A in regs, B in 32-col chunks double-buffered via global_load_lds (XOR
// swizzle). NO cross-block atomics: plain stores to disjoint part[] slots.
__global__ __launch_bounds__(256, 2)
void sim_kernel(const unsigned short* __restrict__ zn, float* __restrict__ part) {
  __shared__ unsigned short lds[2 * CHUNK * DDIM];   // 2 x 8 KB
  __shared__ float colpart[16][CPAD];                // [wave*4+quad][col] ~8.7 KB

  // linear block id -> upper-triangle (tx <= ty) over NT x NT
  int t = blockIdx.x;
  int tx = (int)((129.0f - sqrtf((float)(16641 - 8 * t))) * 0.5f);
  while ((tx + 1) * NT - ((tx + 1) * tx) / 2 <= t) ++tx;
  while (tx * NT - (tx * (tx - 1)) / 2 > t) --tx;
  const int ty = t - (tx * NT - (tx * (tx - 1)) / 2) + tx;
  const bool diag = (tx == ty);

  const int wave = threadIdx.x >> 6;
  const int lane = threadIdx.x & 63;
  const int l15  = lane & 15;
  const int quad = lane >> 4;

  const int row_base = tx * TILE + wave * 32;
  const int col_base = ty * TILE;

  // A fragments: A[m=l15][k=quad*8+j], 2 mi-tiles x 4 k-frags = 32 VGPRs
  bf16x8 a[2][4];
  const unsigned short* abase = zn + (size_t)(row_base + l15) * DDIM + quad * 8;
  #pragma unroll
  for (int mi = 0; mi < 2; ++mi)
    #pragma unroll
    for (int kf = 0; kf < 4; ++kf)
      a[mi][kf] = *(const bf16x8*)(abase + mi * 16 * DDIM + kf * 32);

  float rs[2][4];
  #pragma unroll
  for (int mi = 0; mi < 2; ++mi)
    #pragma unroll
    for (int r = 0; r < 4; ++r) rs[mi][r] = 0.0f;

  // Staging: buffer = 32 B-rows x 16 chunks of 16B; slot t2 -> row t2>>4,
  // chunk (t2&15)^(row&15) [XOR swizzle]. Two 256-lane issues per chunk.
  const int t0 = wave * 64 + lane;
  const int r0 = t0 >> 4,         c0 = (t0 & 15) ^ (r0 & 15);
  const int r1 = (t0 + 256) >> 4, c1 = (t0 & 15) ^ (r1 & 15);
  const unsigned short* gst0 = zn + (size_t)(col_base + r0) * DDIM + c0 * 8;
  const unsigned short* gst1 = zn + (size_t)(col_base + r1) * DDIM + c1 * 8;

  int rdoff[4];
  #pragma unroll
  for (int kf = 0; kf < 4; ++kf)
    rdoff[kf] = l15 * DDIM + (((quad + 4 * kf) ^ l15) << 3);

  // Per-thread colpart slot: s = wave*4+quad, column written per ni is
  // cc*16 + l15 (cc = ch*2+ni in [0,8), visited once -> plain ds_write).
  float* cp = &colpart[wave * 4 + quad][l15];

  glds16(gst0, lds + wave * 512);                    // prime chunk 0 -> buf 0
  glds16(gst1, lds + 2048 + wave * 512);
  __syncthreads();

  for (int ch = 0; ch < 4; ++ch) {
    const int buf = ch & 1;
    if (ch < 3) {                                    // stage chunk ch+1
      const unsigned short* g0 = gst0 + (size_t)(ch + 1) * CHUNK * DDIM;
      const unsigned short* g1 = gst1 + (size_t)(ch + 1) * CHUNK * DDIM;
      unsigned short* lb = lds + ((ch + 1) & 1) * 4096;
      glds16(g0, lb + wave * 512);
      glds16(g1, lb + 2048 + wave * 512);
    }
    const unsigned short* lb = lds + buf * 4096;
    #pragma unroll
    for (int ni = 0; ni < 2; ++ni) {
      bf16x8 b[4];
      #pragma unroll
      for (int kf = 0; kf < 4; ++kf)
        b[kf] = *(const bf16x8*)(lb + ni * 16 * DDIM + rdoff[kf]);
      f32x4 acc[2];
      #pragma unroll
      for (int mi = 0; mi < 2; ++mi) {
        f32x4 z = {0.0f, 0.0f, 0.0f, 0.0f};
        acc[mi] = __builtin_amdgcn_mfma_f32_16x16x32_bf16(a[mi][0], b[0], z, 0, 0, 0);
      }
      #pragma unroll
      for (int kf = 1; kf < 4; ++kf)
        #pragma unroll
        for (int mi = 0; mi < 2; ++mi)
          acc[mi] = __builtin_amdgcn_mfma_f32_16x16x32_bf16(a[mi][kf], b[kf], acc[mi], 0, 0, 0);
      // e feeds this row's sum and (via colpart) the transposed row's sum.
      float cs = 0.0f;
      #pragma unroll
      for (int mi = 0; mi < 2; ++mi)
        #pragma unroll
        for (int r = 0; r < 4; ++r) {
          float e = __builtin_amdgcn_exp2f(acc[mi][r]);
          rs[mi][r] += e;
          cs += e;
        }
      cp[(ch * 2 + ni) * 16] = cs;                   // unique slot: plain store
    }
    __syncthreads();
  }

  // Row side. C/D layout: col=l15, row=quad*4+reg. Plain store, slot ty.
  #pragma unroll
  for (int mi = 0; mi < 2; ++mi)
    #pragma unroll
    for (int r = 0; r < 4; ++r) {
      float v = rs[mi][r];
      v += __shfl_xor(v, 1);
      v += __shfl_xor(v, 2);
      v += __shfl_xor(v, 4);
      v += __shfl_xor(v, 8);
      if (l15 == 0)
        part[(size_t)ty * NROWS + row_base + mi * 16 + quad * 4 + r] = v;
    }
  // Col side: reduce 16 slots per column, plain store, slot tx.
  if (!diag && threadIdx.x < TILE) {
    float v = 0.0f;
    #pragma unroll
    for (int s = 0; s < 16; ++s) v += colpart[s][threadIdx.x];
    part[(size_t)tx * NROWS + col_base + threadIdx.x] = v;
  }
}

// ---- Kernel 3: sum 64 slots per row, logs + mean -------------------------
__global__ void finalize_kernel(const float* __restrict__ part,
                                const float* __restrict__ pos,
                                float* __restrict__ out) {
  __shared__ float red[4];
  int i = blockIdx.x * 256 + threadIdx.x;            // grid 16 x 256 = 4096 pairs
  float si = 0.0f, sp = 0.0f;
  #pragma unroll 8
  for (int s = 0; s < NT; ++s) {
    si += part[(size_t)s * NROWS + i];
    sp += part[(size_t)s * NROWS + i + BHALF];
  }
  si -= EXPDIAG;
  sp -= EXPDIAG;
  float v = logf(si) + logf(sp) - TWO_LN2 * pos[i];
  #pragma unroll
  for (int off = 1; off < 64; off <<= 1) v += __shfl_xor(v, off);
  int wave = threadIdx.x >> 6, lane = threadIdx.x & 63;
  if (lane == 0) red[wave] = v;
  __syncthreads();
  if (threadIdx.x == 0)
    atomicAdd(out, (red[0] + red[1] + red[2] + red[3]) * (1.0f / 8192.0f));
}

extern "C" void kernel_launch(void* const* d_in, const int* in_sizes, int n_in,
                              void* d_out, int out_size, void* d_ws, size_t ws_size,
                              hipStream_t stream) {
  const float* zi = (const float*)d_in[0];
  const float* zj = (const float*)d_in[1];
  char* ws = (char*)d_ws;
  unsigned short* zn = (unsigned short*)ws;                       // 2 MB
  float* part = (float*)(ws + (size_t)NROWS * DDIM * 2);          // 2 MB (64x8192)
  float* pos  = (float*)(ws + (size_t)NROWS * DDIM * 2
                            + (size_t)NT * NROWS * 4);            // 16 KB
  float* out = (float*)d_out;

  norm_kernel<<<2048, 256, 0, stream>>>(zi, zj, zn, pos, out);
  sim_kernel<<<NBLK, 256, 0, stream>>>(zn, part);
  finalize_kernel<<<16, 256, 0, stream>>>(part, pos, out);
}

// Round 5
// 81.184 us; speedup vs baseline: 1.8293x; 1.0658x over previous
//
#include <hip/hip_runtime.h>
#include <hip/hip_bf16.h>
#include <math.h>

// NTXent loss, N=8192 rows, D=128.
// loss = mean_i [ log(sum_{j!=i} exp(2*cos_ij)) - 2*cos_{i,partner} ]
// R13: every round shows total = sim + ~45us fixed floor (poison fill +
// dispatch overhead). sim (~35-40us vs ~3us issue-bound) is a textbook
// 2-phase schedule: per-chunk implicit vmcnt(0)+s_barrier drain (m233: ~72%
// overhead regime). Port T3/T4: B-panel is only 32 KB -> issue ALL 4 chunks'
// global_load_lds in the prologue (4 disjoint buffers), then per chunk
// {asm s_waitcnt vmcnt(6/4/2/0) -> raw s_barrier -> sched_barrier(0) ->
// ds_read+MFMA+exp2}. Loads stay in flight across barriers; no vmcnt(0)
// in the loop. A-loads pinned before glds (sched_barrier) so counts are
// exact. T5 setprio kept. colpart unpadded -> 40 KB LDS, 4 blocks/CU.
// finalize: 32 blocks (per-row split) to halve its tail.

typedef __attribute__((ext_vector_type(8))) short bf16x8;   // 8 bf16 = 4 VGPRs
typedef __attribute__((ext_vector_type(4))) float f32x4;

#define NROWS 8192
#define DDIM  128
#define BHALF 4096
#define CHUNK 32
#define TILE  128
#define NT    64                    // 64x64 grid of 128x128 tiles
#define NBLK  2080                  // 64*65/2 upper-triangle tiles
#define CPAD  128                   // unpadded: epilogue reads stride-1
// zn scaled by sqrt(2/ln2): acc = (2/ln2)*cos, exp(2cos) = exp2(acc)
#define SQRT_E2S 1.6986435980707531f
#define TWO_LN2  1.3862943611198906f
#define LN2      0.6931471805599453f
#define EXPDIAG  7.38905609893065f

static __device__ __forceinline__ unsigned short f2bf(float f) {
  unsigned int u = __float_as_uint(f);
  unsigned int r = (u + 0x7fffu + ((u >> 16) & 1u)) >> 16;   // RNE
  return (unsigned short)r;
}

static __device__ __forceinline__ void glds16(const unsigned short* g, unsigned short* l) {
  __builtin_amdgcn_global_load_lds((const __attribute__((address_space(1))) unsigned int*)g,
                                   (__attribute__((address_space(3))) unsigned int*)l,
                                   16, 0, 0);
}

// ---- Kernel 1: normalize (scaled) + fp32 pair-dots + zero out ------------
// Block b: waves 0,1 -> rows 2b,2b+1 (zi); waves 2,3 -> their partners (zj).
__global__ void norm_kernel(const float* __restrict__ zi, const float* __restrict__ zj,
                            unsigned short* __restrict__ zn,
                            float* __restrict__ pos, float* __restrict__ out) {
  __shared__ float2 xbuf[2][64];
  int wave = threadIdx.x >> 6;
  int lane = threadIdx.x & 63;
  int pi   = blockIdx.x * 2 + (wave & 1);           // pair index
  int row  = pi + (wave >> 1) * BHALF;
  const float* src = (row < BHALF) ? (zi + (size_t)row * DDIM)
                                   : (zj + (size_t)(row - BHALF) * DDIM);
  float2 v = *(const float2*)(src + 2 * lane);
  float ss = v.x * v.x + v.y * v.y;
  #pragma unroll
  for (int off = 1; off < 64; off <<= 1) ss += __shfl_xor(ss, off);
  float scale = SQRT_E2S / fmaxf(sqrtf(ss), 1e-8f);
  v.x *= scale; v.y *= scale;
  unsigned int lo = f2bf(v.x), hi = f2bf(v.y);
  ((unsigned int*)(zn + (size_t)row * DDIM))[lane] = lo | (hi << 16);

  if (wave >= 2) xbuf[wave - 2][lane] = v;
  __syncthreads();
  if (wave < 2) {                                    // d = (2/ln2)*cos(i, i+B)
    float2 w = xbuf[wave][lane];
    float d = v.x * w.x + v.y * w.y;
    #pragma unroll
    for (int off = 1; off < 64; off <<= 1) d += __shfl_xor(d, off);
    if (lane == 0) pos[pi] = d;
  }
  if (blockIdx.x == 0 && threadIdx.x == 0) out[0] = 0.0f;
}

// ---- Kernel 2: upper-triangle sim + exp + row/col partial sums -----------
// 2080 blocks, 128x128 tiles, 4 waves x 32 rows, A in regs. Whole B-panel
// (32 KB) staged once via 8 prologue global_load_lds per thread into 4
// disjoint chunk buffers; per chunk: counted vmcnt + raw barrier (no drain).
__global__ __launch_bounds__(256, 2)
void sim_kernel(const unsigned short* __restrict__ zn, float* __restrict__ part) {
  __shared__ unsigned short lds[4 * CHUNK * DDIM];   // 4 x 8 KB, single-shot
  __shared__ float colpart[16][CPAD];                // 8 KB

  // linear block id -> upper-triangle (tx <= ty) over NT x NT
  int t = blockIdx.x;
  int tx = (int)((129.0f - sqrtf((float)(16641 - 8 * t))) * 0.5f);
  while ((tx + 1) * NT - ((tx + 1) * tx) / 2 <= t) ++tx;
  while (tx * NT - (tx * (tx - 1)) / 2 > t) --tx;
  const int ty = t - (tx * NT - (tx * (tx - 1)) / 2) + tx;
  const bool diag = (tx == ty);

  const int wave = threadIdx.x >> 6;
  const int lane = threadIdx.x & 63;
  const int l15  = lane & 15;
  const int quad = lane >> 4;

  const int row_base = tx * TILE + wave * 32;
  const int col_base = ty * TILE;

  // A fragments: A[m=l15][k=quad*8+j], 2 mi-tiles x 4 k-frags = 32 VGPRs.
  // Issued FIRST (oldest in vmcnt order), pinned by sched_barrier below.
  bf16x8 a[2][4];
  const unsigned short* abase = zn + (size_t)(row_base + l15) * DDIM + quad * 8;
  #pragma unroll
  for (int mi = 0; mi < 2; ++mi)
    #pragma unroll
    for (int kf = 0; kf < 4; ++kf)
      a[mi][kf] = *(const bf16x8*)(abase + mi * 16 * DDIM + kf * 32);
  __builtin_amdgcn_sched_barrier(0);   // pin: A-loads strictly before glds

  // Staging: chunk buffer = 32 B-rows x 16 slots of 16B; slot t2 -> row
  // t2>>4, col-chunk (t2&15)^(row&15) [XOR swizzle]. 2 issues per chunk per
  // thread; all 4 chunks issued up front (8 outstanding after prologue).
  const int t0 = wave * 64 + lane;
  const int r0 = t0 >> 4,         c0 = (t0 & 15) ^ (r0 & 15);
  const int r1 = (t0 + 256) >> 4, c1 = (t0 & 15) ^ (r1 & 15);
  const unsigned short* gst0 = zn + (size_t)(col_base + r0) * DDIM + c0 * 8;
  const unsigned short* gst1 = zn + (size_t)(col_base + r1) * DDIM + c1 * 8;
  #pragma unroll
  for (int ch = 0; ch < 4; ++ch) {
    glds16(gst0 + (size_t)ch * CHUNK * DDIM, lds + ch * 4096 + wave * 512);
    glds16(gst1 + (size_t)ch * CHUNK * DDIM, lds + ch * 4096 + 2048 + wave * 512);
  }
  __builtin_amdgcn_sched_barrier(0);   // pin: all glds issued before loop

  int rdoff[4];
  #pragma unroll
  for (int kf = 0; kf < 4; ++kf)
    rdoff[kf] = l15 * DDIM + (((quad + 4 * kf) ^ l15) << 3);

  float rs[2][4];
  #pragma unroll
  for (int mi = 0; mi < 2; ++mi)
    #pragma unroll
    for (int r = 0; r < 4; ++r) rs[mi][r] = 0.0f;

  // Per-thread colpart slot: s = wave*4+quad, column (cc*16+l15), cc=ch*2+ni
  // visited once per thread -> plain ds_write, no init needed.
  float* cp = &colpart[wave * 4 + quad][l15];

// Per-chunk phase: counted vmcnt (own staging for this chunk retired) ->
// raw barrier (all waves' staging for this chunk retired) -> compute.
#define SIM_PHASE(CH, VM)                                                      \
  {                                                                            \
    asm volatile("s_waitcnt vmcnt(" VM ")" ::: "memory");                      \
    __builtin_amdgcn_s_barrier();                                              \
    __builtin_amdgcn_sched_barrier(0);                                         \
    const unsigned short* lb = lds + (CH) * 4096;                              \
    _Pragma("unroll")                                                          \
    for (int ni = 0; ni < 2; ++ni) {                                           \
      bf16x8 b[4];                                                             \
      _Pragma("unroll")                                                        \
      for (int kf = 0; kf < 4; ++kf)                                           \
        b[kf] = *(const bf16x8*)(lb + ni * 16 * DDIM + rdoff[kf]);             \
      f32x4 acc[2];                                                            \
      __builtin_amdgcn_s_setprio(1);                                           \
      _Pragma("unroll")                                                        \
      for (int mi = 0; mi < 2; ++mi) {                                         \
        f32x4 z = {0.0f, 0.0f, 0.0f, 0.0f};                                    \
        acc[mi] = __builtin_amdgcn_mfma_f32_16x16x32_bf16(a[mi][0], b[0], z, 0, 0, 0); \
      }                                                                        \
      _Pragma("unroll")                                                        \
      for (int kf = 1; kf < 4; ++kf)                                           \
        _Pragma("unroll")                                                      \
        for (int mi = 0; mi < 2; ++mi)                                         \
          acc[mi] = __builtin_amdgcn_mfma_f32_16x16x32_bf16(a[mi][kf], b[kf], acc[mi], 0, 0, 0); \
      __builtin_amdgcn_s_setprio(0);                                           \
      float cs = 0.0f;                                                         \
      _Pragma("unroll")                                                        \
      for (int mi = 0; mi < 2; ++mi)                                           \
        _Pragma("unroll")                                                      \
        for (int r = 0; r < 4; ++r) {                                          \
          float e = __builtin_amdgcn_exp2f(acc[mi][r]);                        \
          rs[mi][r] += e;                                                      \
          cs += e;                                                             \
        }                                                                      \
      cp[((CH) * 2 + ni) * 16] = cs;                                           \
    }                                                                          \
  }

  SIM_PHASE(0, "6")
  SIM_PHASE(1, "4")
  SIM_PHASE(2, "2")
  SIM_PHASE(3, "0")
#undef SIM_PHASE

  // Row side. C/D layout: col=l15, row=quad*4+reg. Plain store, slot ty.
  #pragma unroll
  for (int mi = 0; mi < 2; ++mi)
    #pragma unroll
    for (int r = 0; r < 4; ++r) {
      float v = rs[mi][r];
      v += __shfl_xor(v, 1);
      v += __shfl_xor(v, 2);
      v += __shfl_xor(v, 4);
      v += __shfl_xor(v, 8);
      if (l15 == 0)
        part[(size_t)ty * NROWS + row_base + mi * 16 + quad * 4 + r] = v;
    }
  // Col side: reduce 16 slots per column, plain store, slot tx.
  __syncthreads();
  if (!diag && threadIdx.x < TILE) {
    float v = 0.0f;
    #pragma unroll
    for (int s = 0; s < 16; ++s) v += colpart[s][threadIdx.x];
    part[(size_t)tx * NROWS + col_base + threadIdx.x] = v;
  }
}

// ---- Kernel 3: sum 64 slots per row, logs + mean (per-row split) ---------
__global__ void finalize_kernel(const float* __restrict__ part,
                                const float* __restrict__ pos,
                                float* __restrict__ out) {
  __shared__ float red[4];
  int r = blockIdx.x * 256 + threadIdx.x;            // grid 32 x 256 = 8192 rows
  float s = 0.0f;
  #pragma unroll 16
  for (int k = 0; k < NT; ++k) s += part[(size_t)k * NROWS + r];
  // per row: log(rowsum_negs) - 2*cos_pos = log(s - e^2) - ln2 * pos
  float v = logf(s - EXPDIAG) - LN2 * pos[r & (BHALF - 1)];
  #pragma unroll
  for (int off = 1; off < 64; off <<= 1) v += __shfl_xor(v, off);
  int wave = threadIdx.x >> 6, lane = threadIdx.x & 63;
  if (lane == 0) red[wave] = v;
  __syncthreads();
  if (threadIdx.x == 0)
    atomicAdd(out, (red[0] + red[1] + red[2] + red[3]) * (1.0f / 8192.0f));
}

extern "C" void kernel_launch(void* const* d_in, const int* in_sizes, int n_in,
                              void* d_out, int out_size, void* d_ws, size_t ws_size,
                              hipStream_t stream) {
  const float* zi = (const float*)d_in[0];
  const float* zj = (const float*)d_in[1];
  char* ws = (char*)d_ws;
  unsigned short* zn = (unsigned short*)ws;                       // 2 MB
  float* part = (float*)(ws + (size_t)NROWS * DDIM * 2);          // 2 MB (64x8192)
  float* pos  = (float*)(ws + (size_t)NROWS * DDIM * 2
                            + (size_t)NT * NROWS * 4);            // 16 KB
  float* out = (float*)d_out;

  norm_kernel<<<2048, 256, 0, stream>>>(zi, zj, zn, pos, out);
  sim_kernel<<<NBLK, 256, 0, stream>>>(zn, part);
  finalize_kernel<<<32, 256, 0, stream>>>(part, pos, out);
}

// Round 6
// 81.060 us; speedup vs baseline: 1.8321x; 1.0015x over previous
//
#include <hip/hip_runtime.h>
#include <hip/hip_bf16.h>
#include <math.h>

// NTXent loss, N=8192 rows, D=128.
// loss = mean_i [ log(sum_{j!=i} exp(2*cos_ij)) - 2*cos_{i,partner} ]
// R14: floor accounting says sim ~31us vs ~8us pipe-work: stall-bound at
// ~1-2 waves/SIMD average (R11 occ 14%), 2080 short-lived blocks paying a
// serial prologue each, allocator told to plan for only 2 blocks/CU.
// Changes: (1) __launch_bounds__(256,4): body live state ~100 VGPR fits the
// 128 cap; LDS 40 KB -> 4 blocks/CU, waves/SIMD 2->4. (2) Two tiles per
// block along a triangle row (same tx): 1056 blocks, A-frags loaded once,
// tile-2 staging issued under tile-1's epilogue; same counted-vmcnt phases.
// (3) finalize: 64 blocks, split-k halves. Spill tripwire: VGPR ~84 +
// WRITE_SIZE blowup => revert bound to ,3.

typedef __attribute__((ext_vector_type(8))) short bf16x8;   // 8 bf16 = 4 VGPRs
typedef __attribute__((ext_vector_type(4))) float f32x4;

#define NROWS 8192
#define DDIM  128
#define BHALF 4096
#define CHUNK 32
#define TILE  128
#define NT    64                    // 64x64 grid of 128x128 tiles
#define NBLKP 1056                  // sum over rows of ceil((NT-tx)/2)
#define CPAD  128
// zn scaled by sqrt(2/ln2): acc = (2/ln2)*cos, exp(2cos) = exp2(acc)
#define SQRT_E2S 1.6986435980707531f
#define LN2      0.6931471805599453f
#define EXPDIAG  7.38905609893065f

static __device__ __forceinline__ unsigned short f2bf(float f) {
  unsigned int u = __float_as_uint(f);
  unsigned int r = (u + 0x7fffu + ((u >> 16) & 1u)) >> 16;   // RNE
  return (unsigned short)r;
}

static __device__ __forceinline__ void glds16(const unsigned short* g, unsigned short* l) {
  __builtin_amdgcn_global_load_lds((const __attribute__((address_space(1))) unsigned int*)g,
                                   (__attribute__((address_space(3))) unsigned int*)l,
                                   16, 0, 0);
}

// pair-prefix over triangle rows: P(x) = sum_{r<x} ceil((64-r)/2)
static __device__ __forceinline__ int pfx(int x) {
  int u = x >> 1;
  int base = u * (65 - u);
  return (x & 1) ? base + (32 - u) : base;
}

// ---- Kernel 1: normalize (scaled) + fp32 pair-dots + zero out ------------
// Block b: waves 0,1 -> rows 2b,2b+1 (zi); waves 2,3 -> their partners (zj).
__global__ void norm_kernel(const float* __restrict__ zi, const float* __restrict__ zj,
                            unsigned short* __restrict__ zn,
                            float* __restrict__ pos, float* __restrict__ out) {
  __shared__ float2 xbuf[2][64];
  int wave = threadIdx.x >> 6;
  int lane = threadIdx.x & 63;
  int pi   = blockIdx.x * 2 + (wave & 1);           // pair index
  int row  = pi + (wave >> 1) * BHALF;
  const float* src = (row < BHALF) ? (zi + (size_t)row * DDIM)
                                   : (zj + (size_t)(row - BHALF) * DDIM);
  float2 v = *(const float2*)(src + 2 * lane);
  float ss = v.x * v.x + v.y * v.y;
  #pragma unroll
  for (int off = 1; off < 64; off <<= 1) ss += __shfl_xor(ss, off);
  float scale = SQRT_E2S / fmaxf(sqrtf(ss), 1e-8f);
  v.x *= scale; v.y *= scale;
  unsigned int lo = f2bf(v.x), hi = f2bf(v.y);
  ((unsigned int*)(zn + (size_t)row * DDIM))[lane] = lo | (hi << 16);

  if (wave >= 2) xbuf[wave - 2][lane] = v;
  __syncthreads();
  if (wave < 2) {                                    // d = (2/ln2)*cos(i, i+B)
    float2 w = xbuf[wave][lane];
    float d = v.x * w.x + v.y * w.y;
    #pragma unroll
    for (int off = 1; off < 64; off <<= 1) d += __shfl_xor(d, off);
    if (lane == 0) pos[pi] = d;
  }
  if (blockIdx.x == 0 && threadIdx.x == 0) out[0] = 0.0f;
}

// ---- Kernel 2: upper-triangle sim + exp + row/col partial sums -----------
// 1056 blocks; each handles 2 tiles (tx, ty0) and (tx, ty0+1) sharing the
// A-panel in registers. Per tile: whole 32 KB B-panel staged via 8
// global_load_lds, 4 phases with counted vmcnt + raw barriers (no drain).
__global__ __launch_bounds__(256, 4)
void sim_kernel(const unsigned short* __restrict__ zn, float* __restrict__ part) {
  __shared__ unsigned short lds[4 * CHUNK * DDIM];   // 4 x 8 KB, single-shot/tile
  __shared__ float colpart[16][CPAD];                // 8 KB

  // block id -> (tx, pair p); tiles ty0 = tx+2p and ty0+1 (if < NT)
  int bid = blockIdx.x;
  int tx = (int)(65.0f - sqrtf(fmaxf(0.0f, 4225.0f - 4.0f * (float)bid)));
  tx = tx < 0 ? 0 : (tx > 63 ? 63 : tx);
  while (pfx(tx + 1) <= bid) ++tx;
  while (pfx(tx) > bid) --tx;
  const int ty0  = tx + 2 * (bid - pfx(tx));
  const bool has2 = (ty0 + 1) < NT;

  const int wave = threadIdx.x >> 6;
  const int lane = threadIdx.x & 63;
  const int l15  = lane & 15;
  const int quad = lane >> 4;

  const int row_base = tx * TILE + wave * 32;

  // A fragments: A[m=l15][k=quad*8+j], 2 mi-tiles x 4 k-frags = 32 VGPRs.
  // Issued FIRST (oldest in vmcnt order), pinned by sched_barrier below.
  bf16x8 a[2][4];
  const unsigned short* abase = zn + (size_t)(row_base + l15) * DDIM + quad * 8;
  #pragma unroll
  for (int mi = 0; mi < 2; ++mi)
    #pragma unroll
    for (int kf = 0; kf < 4; ++kf)
      a[mi][kf] = *(const bf16x8*)(abase + mi * 16 * DDIM + kf * 32);
  __builtin_amdgcn_sched_barrier(0);   // pin: A-loads strictly before glds

  // Staging geometry: chunk buffer = 32 B-rows x 16 slots of 16B; slot
  // t2 = wave*64+lane -> row t2>>4, col-chunk (t2&15)^(row&15) [XOR swizzle].
  const int t0 = wave * 64 + lane;
  const int r0 = t0 >> 4,         c0 = (t0 & 15) ^ (r0 & 15);
  const int r1 = (t0 + 256) >> 4, c1 = (t0 & 15) ^ (r1 & 15);
  const size_t goff0 = (size_t)r0 * DDIM + c0 * 8;
  const size_t goff1 = (size_t)r1 * DDIM + c1 * 8;

  // tile 0 staging: all 4 chunks issued up front (8 outstanding)
  {
    const unsigned short* g0 = zn + (size_t)(ty0 * TILE) * DDIM + goff0;
    const unsigned short* g1 = zn + (size_t)(ty0 * TILE) * DDIM + goff1;
    #pragma unroll
    for (int ch = 0; ch < 4; ++ch) {
      glds16(g0 + (size_t)ch * CHUNK * DDIM, lds + ch * 4096 + wave * 512);
      glds16(g1 + (size_t)ch * CHUNK * DDIM, lds + ch * 4096 + 2048 + wave * 512);
    }
  }
  __builtin_amdgcn_sched_barrier(0);   // pin: glds issued before loop body

  int rdoff[4];
  #pragma unroll
  for (int kf = 0; kf < 4; ++kf)
    rdoff[kf] = l15 * DDIM + (((quad + 4 * kf) ^ l15) << 3);

  // Per-thread colpart slot: s = wave*4+quad, column (cc*16+l15), cc=ch*2+ni
  // visited once per thread per tile -> plain ds_write, no init needed.
  float* cp = &colpart[wave * 4 + quad][l15];

// Per-chunk phase: counted vmcnt (this chunk's staging retired; stores
// issued earlier are older and retire first) -> raw barrier -> compute.
#define SIM_PHASE(CH, VM)                                                      \
  {                                                                            \
    asm volatile("s_waitcnt vmcnt(" VM ")" ::: "memory");                      \
    __builtin_amdgcn_s_barrier();                                              \
    __builtin_amdgcn_sched_barrier(0);                                         \
    const unsigned short* lb = lds + (CH) * 4096;                              \
    _Pragma("unroll")                                                          \
    for (int ni = 0; ni < 2; ++ni) {                                           \
      bf16x8 b[4];                                                             \
      _Pragma("unroll")                                                        \
      for (int kf = 0; kf < 4; ++kf)                                           \
        b[kf] = *(const bf16x8*)(lb + ni * 16 * DDIM + rdoff[kf]);             \
      f32x4 acc[2];                                                            \
      __builtin_amdgcn_s_setprio(1);                                           \
      _Pragma("unroll")                                                        \
      for (int mi = 0; mi < 2; ++mi) {                                         \
        f32x4 z = {0.0f, 0.0f, 0.0f, 0.0f};                                    \
        acc[mi] = __builtin_amdgcn_mfma_f32_16x16x32_bf16(a[mi][0], b[0], z, 0, 0, 0); \
      }                                                                        \
      _Pragma("unroll")                                                        \
      for (int kf = 1; kf < 4; ++kf)                                           \
        _Pragma("unroll")                                                      \
        for (int mi = 0; mi < 2; ++mi)                                         \
          acc[mi] = __builtin_amdgcn_mfma_f32_16x16x32_bf16(a[mi][kf], b[kf], acc[mi], 0, 0, 0); \
      __builtin_amdgcn_s_setprio(0);                                           \
      float cs = 0.0f;                                                         \
      _Pragma("unroll")                                                        \
      for (int mi = 0; mi < 2; ++mi)                                           \
        _Pragma("unroll")                                                      \
        for (int r = 0; r < 4; ++r) {                                          \
          float e = __builtin_amdgcn_exp2f(acc[mi][r]);                        \
          rs[mi][r] += e;                                                      \
          cs += e;                                                             \
        }                                                                      \
      cp[((CH) * 2 + ni) * 16] = cs;                                           \
    }                                                                          \
  }

  for (int tile = 0; tile < 2; ++tile) {
    const int ty = ty0 + tile;
    const bool diag = (ty == tx);                    // only possible at tile 0
    const int col_base = ty * TILE;

    float rs[2][4];
    #pragma unroll
    for (int mi = 0; mi < 2; ++mi)
      #pragma unroll
      for (int r = 0; r < 4; ++r) rs[mi][r] = 0.0f;

    SIM_PHASE(0, "6")
    SIM_PHASE(1, "4")
    SIM_PHASE(2, "2")
    SIM_PHASE(3, "0")

    // Row side. C/D layout: col=l15, row=quad*4+reg. Plain store, slot ty.
    #pragma unroll
    for (int mi = 0; mi < 2; ++mi)
      #pragma unroll
      for (int r = 0; r < 4; ++r) {
        float v = rs[mi][r];
        v += __shfl_xor(v, 1);
        v += __shfl_xor(v, 2);
        v += __shfl_xor(v, 4);
        v += __shfl_xor(v, 8);
        if (l15 == 0)
          part[(size_t)ty * NROWS + row_base + mi * 16 + quad * 4 + r] = v;
      }

    __syncthreads();   // all waves done phase-3 ds_reads + colpart writes

    // issue next tile's staging under this tile's col-epilogue
    if (tile == 0 && has2) {
      const unsigned short* g0 = zn + (size_t)((ty0 + 1) * TILE) * DDIM + goff0;
      const unsigned short* g1 = zn + (size_t)((ty0 + 1) * TILE) * DDIM + goff1;
      #pragma unroll
      for (int ch = 0; ch < 4; ++ch) {
        glds16(g0 + (size_t)ch * CHUNK * DDIM, lds + ch * 4096 + wave * 512);
        glds16(g1 + (size_t)ch * CHUNK * DDIM, lds + ch * 4096 + 2048 + wave * 512);
      }
    }

    // Col side: reduce 16 slots per column (colpart untouched by glds),
    // plain store, slot tx.
    if (!diag && threadIdx.x < TILE) {
      float v = 0.0f;
      #pragma unroll
      for (int s = 0; s < 16; ++s) v += colpart[s][threadIdx.x];
      part[(size_t)tx * NROWS + col_base + threadIdx.x] = v;
    }

    if (!has2) break;
  }
#undef SIM_PHASE
}

// ---- Kernel 3: sum 64 slots per row, logs + mean (64 blocks, split-k) ----
__global__ void finalize_kernel(const float* __restrict__ part,
                                const float* __restrict__ pos,
                                float* __restrict__ out) {
  __shared__ float fsum[128];
  __shared__ float red[2];
  int rloc = threadIdx.x & 127;
  int half = threadIdx.x >> 7;
  int r = blockIdx.x * 128 + rloc;                   // grid 64 x (128 rows)
  float s = 0.0f;
  #pragma unroll 8
  for (int k = half * 32; k < half * 32 + 32; ++k)
    s += part[(size_t)k * NROWS + r];
  if (half == 0) fsum[rloc] = s;
  __syncthreads();
  if (half == 1) fsum[rloc] += s;
  __syncthreads();
  if (threadIdx.x < 128) {
    float tot = fsum[threadIdx.x];
    float v = logf(tot - EXPDIAG) - LN2 * pos[r & (BHALF - 1)];
    #pragma unroll
    for (int off = 1; off < 64; off <<= 1) v += __shfl_xor(v, off);
    if ((threadIdx.x & 63) == 0) red[threadIdx.x >> 6] = v;
  }
  __syncthreads();
  if (threadIdx.x == 0)
    atomicAdd(out, (red[0] + red[1]) * (1.0f / 8192.0f));
}

extern "C" void kernel_launch(void* const* d_in, const int* in_sizes, int n_in,
                              void* d_out, int out_size, void* d_ws, size_t ws_size,
                              hipStream_t stream) {
  const float* zi = (const float*)d_in[0];
  const float* zj = (const float*)d_in[1];
  char* ws = (char*)d_ws;
  unsigned short* zn = (unsigned short*)ws;                       // 2 MB
  float* part = (float*)(ws + (size_t)NROWS * DDIM * 2);          // 2 MB (64x8192)
  float* pos  = (float*)(ws + (size_t)NROWS * DDIM * 2
                            + (size_t)NT * NROWS * 4);            // 16 KB
  float* out = (float*)d_out;

  norm_kernel<<<2048, 256, 0, stream>>>(zi, zj, zn, pos, out);
  sim_kernel<<<NBLKP, 256, 0, stream>>>(zn, part);
  finalize_kernel<<<64, 256, 0, stream>>>(part, pos, out);
}